// Round 18
// baseline (119.363 us; speedup 1.0000x reference)
//
#include <hip/hip_runtime.h>

#define QST 600        // 6*10*10 sites per quad
#define NSITES 2400    // 4 quads
#define PH_OFF 19200   // P half-buffer offset

// LDS map (bytes):
//  [0,19200)      quad tile uint2[2400]: [cq][z 6][y 10][x 10], 4 bf16 channels/site
//  [19200,35584)  P half-buffer bf16: 256 rows x 64B (4 slots), slot swizzle sl^=(row>>1)&3.
//                 TIME-SHARED between feature halves (ks=0: cq0/1, ks=1: cq2/3) — wave-local,
//                 fenced with lgkmcnt(0)+sched_barrier (per-wave LDS ops are in-order in HW).
//  total 35584 B -> 4 blocks/CU with __launch_bounds__(256,4).
//
// d_ws (shorts): [0,8192) W1 frags 1024x16B (sobel cols pre-scaled by 0.125);
//                [8192,10240) W2 frags 256x16B, rows permuted so D-row r = channel
//                2*(r>>2)+(r&1)+8*((r>>1)&1)  (epilogue takes idents from pf regs, no LDS)

typedef __attribute__((ext_vector_type(8))) short bf16x8;
typedef __attribute__((ext_vector_type(4))) float f32x4;
typedef __attribute__((ext_vector_type(2))) float f32x2;

__device__ __forceinline__ unsigned short f2bf(float f) {
    __bf16 h = (__bf16)f;
    return __builtin_bit_cast(unsigned short, h);
}
__device__ __forceinline__ unsigned packbf2(float lo, float hi) {
    return (unsigned)f2bf(lo) | ((unsigned)f2bf(hi) << 16);
}
__device__ __forceinline__ float blo(unsigned u) { return __builtin_bit_cast(float, u << 16); }
__device__ __forceinline__ float bhi(unsigned u) { return __builtin_bit_cast(float, u & 0xffff0000u); }
__device__ __forceinline__ bf16x8 pack8f(const float* s, const float* scl) {
    bf16x8 o;
    #pragma unroll
    for (int k = 0; k < 8; ++k) o[k] = (short)f2bf(s[k] * scl[k & 3]);
    return o;
}

// ---- pre-pass: permute W1/W2 into lane-canonical bf16 MFMA fragments in d_ws ----
__global__ __launch_bounds__(256) void permute_w(
    const float* __restrict__ w1, const float* __restrict__ w2,
    unsigned short* __restrict__ wsW)
{
    const int t = threadIdx.x;
    const float sclW1[4] = {1.f, 0.125f, 0.125f, 0.125f};   // fold sobel /8 into W1
    const float sclId[4] = {1.f, 1.f, 1.f, 1.f};
    #pragma unroll
    for (int j = 0; j < 4; ++j) {
        int w = t + 256 * j;                 // [0,1024)
        int lane = w & 63, f = (w >> 6) & 3, ch = w >> 8;
        int r16 = lane & 15, g = lane >> 4;
        int row = ch * 32 + 8 * (r16 >> 2) + (r16 & 3) + 4 * (f >> 1);  // E: +0, O: +4
        int col = (f & 1) * 32 + g * 8;                                  // ks half
        *(bf16x8*)(wsW + w * 8) = pack8f(w1 + row * 64 + col, sclW1);
    }
    {
        int w = t;                           // [0,256)
        int lane = w & 63, ch = w >> 6;
        int r16 = lane & 15, g = lane >> 4;
        // W2 row permutation: A-row r holds channel 2*(r>>2)+(r&1)+8*((r>>1)&1)
        int ch2 = 2 * (r16 >> 2) + (r16 & 1) + 8 * ((r16 >> 1) & 1);
        *(bf16x8*)(wsW + 8192 + w * 8) = pack8f(w2 + ch2 * 128 + ch * 32 + g * 8, sclId);
    }
}

__global__ __launch_bounds__(256, 4) void nca_fused(
    const float* __restrict__ x, const float* __restrict__ rand_u,
    const unsigned short* __restrict__ wsW, const float* __restrict__ b1,
    float* __restrict__ out)
{
    __shared__ __align__(16) char smem[35584];
    uint2*          tq = (uint2*)smem;
    unsigned short* Ph = (unsigned short*)(smem + PH_OFF);

    const int tid = threadIdx.x;

    // XCD-bijective work swizzle (R15): each XCD gets a contiguous x-fastest slab.
    const int orig = blockIdx.x + 8 * blockIdx.y + 64 * blockIdx.z;
    const int work = (orig & 7) * 512 + (orig >> 3);
    const int gx0 = (work & 7) * 8;
    const int gy0 = ((work >> 3) & 7) * 8;
    const int zb  = work >> 6;
    const int b   = zb >> 4, gz0 = (zb & 15) * 4;
    const int xbase = b * (16 * 262144);

    const int tx = tid & 7, ty = (tid >> 3) & 7, tz = tid >> 6;

    // hoist rand_u load: latency hides under staging + perception
    const float ru = rand_u[b * 262144 + (gz0 + tz) * 4096 + (gy0 + ty) * 64 + (gx0 + tx)];

    // ---- phase 1: stage tile, one (cq,z,y) row per thread (240 active) ----
    if (tid < 240) {
        int cq = tid / 60, rem = tid - cq * 60;
        int z = rem / 10, y = rem - z * 10;
        int gz = gz0 + z - 1, gy = gy0 + y - 1;
        uint4* dst = (uint4*)(tq + cq * QST + z * 100 + y * 10);   // 16B aligned
        if ((unsigned)gz < 64u && (unsigned)gy < 64u) {
            const bool lok = (gx0 > 0), rok = (gx0 < 56);
            const float* base = x + xbase + cq * (4 * 262144) + gz * 4096 + gy * 64 + gx0;
            float va[10], vb[10];
            unsigned wlo[10], whi[10];
            #pragma unroll
            for (int half = 0; half < 2; ++half) {
                #pragma unroll
                for (int cc = 0; cc < 2; ++cc) {
                    const float* bp = base + (2 * half + cc) * 262144;
                    float* v = cc ? vb : va;
                    float4 a4 = *(const float4*)(bp);
                    float4 b4 = *(const float4*)(bp + 4);
                    v[0] = lok ? bp[-1] : 0.f;
                    v[1] = a4.x; v[2] = a4.y; v[3] = a4.z; v[4] = a4.w;
                    v[5] = b4.x; v[6] = b4.y; v[7] = b4.z; v[8] = b4.w;
                    v[9] = rok ? bp[8] : 0.f;
                }
                unsigned* wdst = half ? whi : wlo;
                #pragma unroll
                for (int k = 0; k < 10; ++k) wdst[k] = packbf2(va[k], vb[k]);
            }
            #pragma unroll
            for (int k = 0; k < 5; ++k)
                dst[k] = make_uint4(wlo[2 * k], whi[2 * k], wlo[2 * k + 1], whi[2 * k + 1]);
        } else {
            #pragma unroll
            for (int k = 0; k < 5; ++k)
                dst[k] = make_uint4(0u, 0u, 0u, 0u);
        }
    }
    __syncthreads();

    // ---- phase 2: perception, two feature-half phases time-sharing the P buffer.
    //      Loads INLINE per (i2,j) row (R15 pattern — the R16 q-hoist spilled at 4 waves). ----
    const int lane = tid & 63, wv = tid >> 6;
    const int g = lane >> 4, r16 = lane & 15;
    const int rowbase = (tz * 10 + ty) * 10 + tx;
    const int sw = (tid >> 1) & 3;                 // row slot swizzle

    float pool3 = -1e30f;
    const f32x2 two = 2.f;
    bf16x8 pf[4][2];

    #pragma unroll
    for (int ph = 0; ph < 2; ++ph) {
        #pragma unroll
        for (int ch2 = 0; ch2 < 2; ++ch2) {
            const int cq = 2 * ph + ch2;
            f32x2 s1p[2], s2p[2], s3p[2];
            uint2 idq = make_uint2(0u, 0u);
            #pragma unroll
            for (int pr = 0; pr < 2; ++pr) { s1p[pr] = 0.f; s2p[pr] = 0.f; s3p[pr] = 0.f; }

            #pragma unroll
            for (int i2 = 0; i2 < 3; ++i2) {
                f32x2 Ap[2], Bp[2], Cp[2];
                #pragma unroll
                for (int pr = 0; pr < 2; ++pr) { Ap[pr] = 0.f; Bp[pr] = 0.f; Cp[pr] = 0.f; }
                #pragma unroll
                for (int j = 0; j < 3; ++j) {
                    const uint2* rp = tq + cq * QST + i2 * 100 + j * 10 + rowbase;
                    uint2 q0 = rp[0], q1 = rp[1], q2 = rp[2];
                    f32x2 v0[2] = { {blo(q0.x), bhi(q0.x)}, {blo(q0.y), bhi(q0.y)} };
                    f32x2 v1[2] = { {blo(q1.x), bhi(q1.x)}, {blo(q1.y), bhi(q1.y)} };
                    f32x2 v2[2] = { {blo(q2.x), bhi(q2.x)}, {blo(q2.y), bhi(q2.y)} };
                    if (cq == 0)   // alpha (c=3) = hi of second pair; nested fmax -> v_max3
                        pool3 = fmaxf(pool3, fmaxf(fmaxf(v0[1].y, v1[1].y), v2[1].y));
                    if (i2 == 1 && j == 1) idq = q1;
                    #pragma unroll
                    for (int pr = 0; pr < 2; ++pr) {
                        f32x2 rg = __builtin_elementwise_fma(two, v1[pr], v0[pr] + v2[pr]);
                        f32x2 rd = v2[pr] - v0[pr];
                        if (j == 1) {
                            Ap[pr] = __builtin_elementwise_fma(two, rg, Ap[pr]);
                            Cp[pr] = __builtin_elementwise_fma(two, rd, Cp[pr]);
                        } else {
                            Ap[pr] = Ap[pr] + rg;
                            Cp[pr] = Cp[pr] + rd;
                            if (j == 0) Bp[pr] = Bp[pr] - rg;
                            else        Bp[pr] = Bp[pr] + rg;
                        }
                    }
                }
                #pragma unroll
                for (int pr = 0; pr < 2; ++pr) {
                    if (i2 == 0) {
                        s1p[pr] = s1p[pr] - Ap[pr];
                        s2p[pr] = s2p[pr] + Bp[pr];
                        s3p[pr] = s3p[pr] + Cp[pr];
                    } else if (i2 == 1) {
                        s2p[pr] = __builtin_elementwise_fma(two, Bp[pr], s2p[pr]);
                        s3p[pr] = __builtin_elementwise_fma(two, Cp[pr], s3p[pr]);
                    } else {
                        s1p[pr] = s1p[pr] + Ap[pr];
                        s2p[pr] = s2p[pr] + Bp[pr];
                        s3p[pr] = s3p[pr] + Cp[pr];
                    }
                }
            }
            // pack & write this cq's 8 P-dwords into the half-buffer (slots 2*ch2, 2*ch2+1)
            unsigned short ide[4] = {
                (unsigned short)(idq.x & 0xffffu), (unsigned short)(idq.x >> 16),
                (unsigned short)(idq.y & 0xffffu), (unsigned short)(idq.y >> 16) };
            float s1e[4] = { s1p[0].x, s1p[0].y, s1p[1].x, s1p[1].y };
            float s2e[4] = { s2p[0].x, s2p[0].y, s2p[1].x, s2p[1].y };
            float s3e[4] = { s3p[0].x, s3p[0].y, s3p[1].x, s3p[1].y };
            unsigned pk8[8];
            #pragma unroll
            for (int e = 0; e < 4; ++e) {
                pk8[2 * e]     = (unsigned)ide[e] | ((unsigned)f2bf(s1e[e]) << 16);
                pk8[2 * e + 1] = packbf2(s2e[e], s3e[e]);
            }
            int s0 = (2 * ch2)     ^ sw;
            int s1 = (2 * ch2 + 1) ^ sw;
            *(uint4*)(smem + PH_OFF + tid * 64 + s0 * 16) = make_uint4(pk8[0], pk8[1], pk8[2], pk8[3]);
            *(uint4*)(smem + PH_OFF + tid * 64 + s1 * 16) = make_uint4(pk8[4], pk8[5], pk8[6], pk8[7]);
        }

        // drain writes (wave-local rows), read this half's B-fragments, drain reads
        asm volatile("s_waitcnt lgkmcnt(0)" ::: "memory");
        __builtin_amdgcn_sched_barrier(0);
        #pragma unroll
        for (int n = 0; n < 4; ++n) {
            int v = (4 * wv + n) * 16 + r16;
            int sl = g ^ ((v >> 1) & 3);
            pf[n][ph] = *(const bf16x8*)(Ph + v * 32 + sl * 8);
        }
        asm volatile("s_waitcnt lgkmcnt(0)" ::: "memory");
        __builtin_amdgcn_sched_barrier(0);
    }
    // masks in a register: bit0 = alive, bit1 = msu (= smask*alive)
    int mpack = (pool3 > 0.1f) ? ((ru <= 0.5f) ? 3 : 1) : 0;

    // ---- phase 3: MFMA. GEMM1: h^T = W1p . P^T (bias in C); GEMM2: upd^T = W2p . h^T ----
    f32x4 acc2[4] = {{0,0,0,0},{0,0,0,0},{0,0,0,0},{0,0,0,0}};
    const f32x4 z4 = {0,0,0,0};

    #pragma unroll
    for (int ch = 0; ch < 4; ++ch) {
        const bf16x8 aE0 = *(const bf16x8*)(wsW + ((ch * 4 + 0) * 64 + lane) * 8);
        const bf16x8 aE1 = *(const bf16x8*)(wsW + ((ch * 4 + 1) * 64 + lane) * 8);
        const bf16x8 aO0 = *(const bf16x8*)(wsW + ((ch * 4 + 2) * 64 + lane) * 8);
        const bf16x8 aO1 = *(const bf16x8*)(wsW + ((ch * 4 + 3) * 64 + lane) * 8);
        const bf16x8 w2f = *(const bf16x8*)(wsW + 8192 + (ch * 64 + lane) * 8);
        const float4 bE4 = *(const float4*)(b1 + ch * 32 + 8 * g);
        const float4 bO4 = *(const float4*)(b1 + ch * 32 + 8 * g + 4);
        const f32x4 cE = {bE4.x, bE4.y, bE4.z, bE4.w};   // bias as accumulator init
        const f32x4 cO = {bO4.x, bO4.y, bO4.z, bO4.w};

        #pragma unroll
        for (int n = 0; n < 4; ++n) {
            f32x4 accE, accO;
            accE = __builtin_amdgcn_mfma_f32_16x16x32_bf16(aE0, pf[n][0], cE, 0, 0, 0);
            accE = __builtin_amdgcn_mfma_f32_16x16x32_bf16(aE1, pf[n][1], accE, 0, 0, 0);
            accO = __builtin_amdgcn_mfma_f32_16x16x32_bf16(aO0, pf[n][0], cO, 0, 0, 0);
            accO = __builtin_amdgcn_mfma_f32_16x16x32_bf16(aO1, pf[n][1], accO, 0, 0, 0);
            f32x4 mE = __builtin_elementwise_max(accE, z4);   // v_pk_max_f32 pairs
            f32x4 mO = __builtin_elementwise_max(accO, z4);
            bf16x8 hb;
            hb[0] = (short)f2bf(mE[0]); hb[1] = (short)f2bf(mE[1]);
            hb[2] = (short)f2bf(mE[2]); hb[3] = (short)f2bf(mE[3]);
            hb[4] = (short)f2bf(mO[0]); hb[5] = (short)f2bf(mO[1]);
            hb[6] = (short)f2bf(mO[2]); hb[7] = (short)f2bf(mO[3]);
            acc2[n] = __builtin_amdgcn_mfma_f32_16x16x32_bf16(w2f, hb, acc2[n], 0, 0, 0);
        }
    }

    // ---- phase 4: epilogue. acc2[n][reg] is channel 2g+(reg&1)+8*(reg>>1) (W2 row perm);
    //      ident of that channel = element 4*(reg&1) of pf[n][reg>>1]. No LDS reads. ----
    #pragma unroll
    for (int n = 0; n < 4; ++n) {
        int v = (4 * wv + n) * 16 + r16;
        int mb = __shfl(mpack, 16 * n + r16, 64);    // owner lane of voxel v (same wave)
        float al = (float)(mb & 1), mu = (float)(mb >> 1);
        int vx = v & 7, vy = (v >> 3) & 7;
        int gidx = xbase + (gz0 + wv) * 4096 + (gy0 + vy) * 64 + (gx0 + vx);
        #pragma unroll
        for (int reg = 0; reg < 4; ++reg) {
            int c = 2 * g + (reg & 1) + 8 * (reg >> 1);
            unsigned short cs = (unsigned short)pf[n][reg >> 1][(reg & 1) * 4];
            float xc = __builtin_bit_cast(float, (unsigned)cs << 16);
            out[gidx + c * 262144] = xc * al + acc2[n][reg] * mu;
        }
    }
}

extern "C" void kernel_launch(void* const* d_in, const int* in_sizes, int n_in,
                              void* d_out, int out_size, void* d_ws, size_t ws_size,
                              hipStream_t stream)
{
    const float* x      = (const float*)d_in[0];
    const float* rand_u = (const float*)d_in[1];
    const float* w1     = (const float*)d_in[2];
    const float* b1     = (const float*)d_in[3];
    const float* w2     = (const float*)d_in[4];
    float* out = (float*)d_out;
    unsigned short* wsW = (unsigned short*)d_ws;   // 20.5 KB used

    permute_w<<<dim3(1), dim3(256), 0, stream>>>(w1, w2, wsW);

    dim3 grid(8, 8, 64);
    dim3 block(256);
    nca_fused<<<grid, block, 0, stream>>>(x, rand_u, wsW, b1, out);
}

// Round 19
// 93.169 us; speedup vs baseline: 1.2811x; 1.2811x over previous
//
#include <hip/hip_runtime.h>

#define QST 600        // 6*10*10 sites per quad
#define NSITES 2400    // 4 quads
#define PH_OFF 19200   // P half-buffer offset

// LDS map (bytes):
//  [0,19200)      quad tile uint2[2400]: [cq][z 6][y 10][x 10], 4 bf16 channels/site
//  [19200,35584)  P half-buffer bf16: 256 rows x 64B (4 slots), slot swizzle sl^=(row>>1)&3.
//                 TIME-SHARED between feature halves (ks=0: cq0/1, ks=1: cq2/3) — wave-local,
//                 fenced with lgkmcnt(0)+sched_barrier (per-wave LDS ops are in-order in HW).
//  total 35584 B. NOTE: __launch_bounds__(256,3) — 4 waves/SIMD spills (R8/R17/R18:
//  live set pf+staging+perception ≈150 regs > 128 cap). 3 blocks/CU is the operating point.
//
// d_ws (shorts): [0,8192) W1 frags 1024x16B (sobel cols pre-scaled by 0.125);
//                [8192,10240) W2 frags 256x16B, rows permuted so D-row r = channel
//                2*(r>>2)+(r&1)+8*((r>>1)&1)  (epilogue takes idents from pf regs, no LDS)

typedef __attribute__((ext_vector_type(8))) short bf16x8;
typedef __attribute__((ext_vector_type(4))) float f32x4;
typedef __attribute__((ext_vector_type(2))) float f32x2;

__device__ __forceinline__ unsigned short f2bf(float f) {
    __bf16 h = (__bf16)f;
    return __builtin_bit_cast(unsigned short, h);
}
__device__ __forceinline__ unsigned packbf2(float lo, float hi) {
    return (unsigned)f2bf(lo) | ((unsigned)f2bf(hi) << 16);
}
__device__ __forceinline__ float blo(unsigned u) { return __builtin_bit_cast(float, u << 16); }
__device__ __forceinline__ float bhi(unsigned u) { return __builtin_bit_cast(float, u & 0xffff0000u); }
__device__ __forceinline__ bf16x8 pack8f(const float* s, const float* scl) {
    bf16x8 o;
    #pragma unroll
    for (int k = 0; k < 8; ++k) o[k] = (short)f2bf(s[k] * scl[k & 3]);
    return o;
}

// ---- pre-pass: permute W1/W2 into lane-canonical bf16 MFMA fragments in d_ws ----
__global__ __launch_bounds__(256) void permute_w(
    const float* __restrict__ w1, const float* __restrict__ w2,
    unsigned short* __restrict__ wsW)
{
    const int t = threadIdx.x;
    const float sclW1[4] = {1.f, 0.125f, 0.125f, 0.125f};   // fold sobel /8 into W1
    const float sclId[4] = {1.f, 1.f, 1.f, 1.f};
    #pragma unroll
    for (int j = 0; j < 4; ++j) {
        int w = t + 256 * j;                 // [0,1024)
        int lane = w & 63, f = (w >> 6) & 3, ch = w >> 8;
        int r16 = lane & 15, g = lane >> 4;
        int row = ch * 32 + 8 * (r16 >> 2) + (r16 & 3) + 4 * (f >> 1);  // E: +0, O: +4
        int col = (f & 1) * 32 + g * 8;                                  // ks half
        *(bf16x8*)(wsW + w * 8) = pack8f(w1 + row * 64 + col, sclW1);
    }
    {
        int w = t;                           // [0,256)
        int lane = w & 63, ch = w >> 6;
        int r16 = lane & 15, g = lane >> 4;
        // W2 row permutation: A-row r holds channel 2*(r>>2)+(r&1)+8*((r>>1)&1)
        int ch2 = 2 * (r16 >> 2) + (r16 & 1) + 8 * ((r16 >> 1) & 1);
        *(bf16x8*)(wsW + 8192 + w * 8) = pack8f(w2 + ch2 * 128 + ch * 32 + g * 8, sclId);
    }
}

__global__ __launch_bounds__(256, 3) void nca_fused(
    const float* __restrict__ x, const float* __restrict__ rand_u,
    const unsigned short* __restrict__ wsW, const float* __restrict__ b1,
    float* __restrict__ out)
{
    __shared__ __align__(16) char smem[35584];
    uint2*          tq = (uint2*)smem;
    unsigned short* Ph = (unsigned short*)(smem + PH_OFF);

    const int tid = threadIdx.x;

    // XCD-bijective work swizzle (R15): each XCD gets a contiguous x-fastest slab.
    const int orig = blockIdx.x + 8 * blockIdx.y + 64 * blockIdx.z;
    const int work = (orig & 7) * 512 + (orig >> 3);
    const int gx0 = (work & 7) * 8;
    const int gy0 = ((work >> 3) & 7) * 8;
    const int zb  = work >> 6;
    const int b   = zb >> 4, gz0 = (zb & 15) * 4;
    const int xbase = b * (16 * 262144);

    const int tx = tid & 7, ty = (tid >> 3) & 7, tz = tid >> 6;

    // hoist rand_u load: latency hides under staging + perception
    const float ru = rand_u[b * 262144 + (gz0 + tz) * 4096 + (gy0 + ty) * 64 + (gx0 + tx)];

    // ---- phase 1: stage tile, one (cq,z,y) row per thread (240 active) ----
    if (tid < 240) {
        int cq = tid / 60, rem = tid - cq * 60;
        int z = rem / 10, y = rem - z * 10;
        int gz = gz0 + z - 1, gy = gy0 + y - 1;
        uint4* dst = (uint4*)(tq + cq * QST + z * 100 + y * 10);   // 16B aligned
        if ((unsigned)gz < 64u && (unsigned)gy < 64u) {
            const bool lok = (gx0 > 0), rok = (gx0 < 56);
            const float* base = x + xbase + cq * (4 * 262144) + gz * 4096 + gy * 64 + gx0;
            float va[10], vb[10];
            unsigned wlo[10], whi[10];
            #pragma unroll
            for (int half = 0; half < 2; ++half) {
                #pragma unroll
                for (int cc = 0; cc < 2; ++cc) {
                    const float* bp = base + (2 * half + cc) * 262144;
                    float* v = cc ? vb : va;
                    float4 a4 = *(const float4*)(bp);
                    float4 b4 = *(const float4*)(bp + 4);
                    v[0] = lok ? bp[-1] : 0.f;
                    v[1] = a4.x; v[2] = a4.y; v[3] = a4.z; v[4] = a4.w;
                    v[5] = b4.x; v[6] = b4.y; v[7] = b4.z; v[8] = b4.w;
                    v[9] = rok ? bp[8] : 0.f;
                }
                unsigned* wdst = half ? whi : wlo;
                #pragma unroll
                for (int k = 0; k < 10; ++k) wdst[k] = packbf2(va[k], vb[k]);
            }
            #pragma unroll
            for (int k = 0; k < 5; ++k)
                dst[k] = make_uint4(wlo[2 * k], whi[2 * k], wlo[2 * k + 1], whi[2 * k + 1]);
        } else {
            #pragma unroll
            for (int k = 0; k < 5; ++k)
                dst[k] = make_uint4(0u, 0u, 0u, 0u);
        }
    }
    __syncthreads();

    // ---- phase 2: perception, two feature-half phases time-sharing the P buffer ----
    const int lane = tid & 63, wv = tid >> 6;
    const int g = lane >> 4, r16 = lane & 15;
    const int rowbase = (tz * 10 + ty) * 10 + tx;
    const int sw = (tid >> 1) & 3;                 // row slot swizzle

    float pool3 = -1e30f;
    const f32x2 two = 2.f;
    bf16x8 pf[4][2];

    #pragma unroll
    for (int ph = 0; ph < 2; ++ph) {
        #pragma unroll
        for (int ch2 = 0; ch2 < 2; ++ch2) {
            const int cq = 2 * ph + ch2;
            f32x2 s1p[2], s2p[2], s3p[2];
            uint2 idq = make_uint2(0u, 0u);
            #pragma unroll
            for (int pr = 0; pr < 2; ++pr) { s1p[pr] = 0.f; s2p[pr] = 0.f; s3p[pr] = 0.f; }

            #pragma unroll
            for (int i2 = 0; i2 < 3; ++i2) {
                f32x2 Ap[2], Bp[2], Cp[2];
                #pragma unroll
                for (int pr = 0; pr < 2; ++pr) { Ap[pr] = 0.f; Bp[pr] = 0.f; Cp[pr] = 0.f; }
                #pragma unroll
                for (int j = 0; j < 3; ++j) {
                    const uint2* rp = tq + cq * QST + i2 * 100 + j * 10 + rowbase;
                    uint2 q0 = rp[0], q1 = rp[1], q2 = rp[2];
                    f32x2 v0[2] = { {blo(q0.x), bhi(q0.x)}, {blo(q0.y), bhi(q0.y)} };
                    f32x2 v1[2] = { {blo(q1.x), bhi(q1.x)}, {blo(q1.y), bhi(q1.y)} };
                    f32x2 v2[2] = { {blo(q2.x), bhi(q2.x)}, {blo(q2.y), bhi(q2.y)} };
                    if (cq == 0)   // alpha (c=3) = hi of second pair; nested fmax -> v_max3
                        pool3 = fmaxf(pool3, fmaxf(fmaxf(v0[1].y, v1[1].y), v2[1].y));
                    if (i2 == 1 && j == 1) idq = q1;
                    #pragma unroll
                    for (int pr = 0; pr < 2; ++pr) {
                        f32x2 rg = __builtin_elementwise_fma(two, v1[pr], v0[pr] + v2[pr]);
                        f32x2 rd = v2[pr] - v0[pr];
                        if (j == 1) {
                            Ap[pr] = __builtin_elementwise_fma(two, rg, Ap[pr]);
                            Cp[pr] = __builtin_elementwise_fma(two, rd, Cp[pr]);
                        } else {
                            Ap[pr] = Ap[pr] + rg;
                            Cp[pr] = Cp[pr] + rd;
                            if (j == 0) Bp[pr] = Bp[pr] - rg;
                            else        Bp[pr] = Bp[pr] + rg;
                        }
                    }
                }
                #pragma unroll
                for (int pr = 0; pr < 2; ++pr) {
                    if (i2 == 0) {
                        s1p[pr] = s1p[pr] - Ap[pr];
                        s2p[pr] = s2p[pr] + Bp[pr];
                        s3p[pr] = s3p[pr] + Cp[pr];
                    } else if (i2 == 1) {
                        s2p[pr] = __builtin_elementwise_fma(two, Bp[pr], s2p[pr]);
                        s3p[pr] = __builtin_elementwise_fma(two, Cp[pr], s3p[pr]);
                    } else {
                        s1p[pr] = s1p[pr] + Ap[pr];
                        s2p[pr] = s2p[pr] + Bp[pr];
                        s3p[pr] = s3p[pr] + Cp[pr];
                    }
                }
            }
            // pack & write this cq's 8 P-dwords into the half-buffer (slots 2*ch2, 2*ch2+1)
            unsigned short ide[4] = {
                (unsigned short)(idq.x & 0xffffu), (unsigned short)(idq.x >> 16),
                (unsigned short)(idq.y & 0xffffu), (unsigned short)(idq.y >> 16) };
            float s1e[4] = { s1p[0].x, s1p[0].y, s1p[1].x, s1p[1].y };
            float s2e[4] = { s2p[0].x, s2p[0].y, s2p[1].x, s2p[1].y };
            float s3e[4] = { s3p[0].x, s3p[0].y, s3p[1].x, s3p[1].y };
            unsigned pk8[8];
            #pragma unroll
            for (int e = 0; e < 4; ++e) {
                pk8[2 * e]     = (unsigned)ide[e] | ((unsigned)f2bf(s1e[e]) << 16);
                pk8[2 * e + 1] = packbf2(s2e[e], s3e[e]);
            }
            int s0 = (2 * ch2)     ^ sw;
            int s1 = (2 * ch2 + 1) ^ sw;
            *(uint4*)(smem + PH_OFF + tid * 64 + s0 * 16) = make_uint4(pk8[0], pk8[1], pk8[2], pk8[3]);
            *(uint4*)(smem + PH_OFF + tid * 64 + s1 * 16) = make_uint4(pk8[4], pk8[5], pk8[6], pk8[7]);
        }

        // drain writes (wave-local rows), read this half's B-fragments, drain reads
        asm volatile("s_waitcnt lgkmcnt(0)" ::: "memory");
        __builtin_amdgcn_sched_barrier(0);
        #pragma unroll
        for (int n = 0; n < 4; ++n) {
            int v = (4 * wv + n) * 16 + r16;
            int sl = g ^ ((v >> 1) & 3);
            pf[n][ph] = *(const bf16x8*)(Ph + v * 32 + sl * 8);
        }
        asm volatile("s_waitcnt lgkmcnt(0)" ::: "memory");
        __builtin_amdgcn_sched_barrier(0);
    }
    // masks in a register: bit0 = alive, bit1 = msu (= smask*alive)
    int mpack = (pool3 > 0.1f) ? ((ru <= 0.5f) ? 3 : 1) : 0;

    // ---- phase 3: MFMA. GEMM1: h^T = W1p . P^T (bias in C); GEMM2: upd^T = W2p . h^T ----
    f32x4 acc2[4] = {{0,0,0,0},{0,0,0,0},{0,0,0,0},{0,0,0,0}};
    const f32x4 z4 = {0,0,0,0};

    #pragma unroll
    for (int ch = 0; ch < 4; ++ch) {
        const bf16x8 aE0 = *(const bf16x8*)(wsW + ((ch * 4 + 0) * 64 + lane) * 8);
        const bf16x8 aE1 = *(const bf16x8*)(wsW + ((ch * 4 + 1) * 64 + lane) * 8);
        const bf16x8 aO0 = *(const bf16x8*)(wsW + ((ch * 4 + 2) * 64 + lane) * 8);
        const bf16x8 aO1 = *(const bf16x8*)(wsW + ((ch * 4 + 3) * 64 + lane) * 8);
        const bf16x8 w2f = *(const bf16x8*)(wsW + 8192 + (ch * 64 + lane) * 8);
        const float4 bE4 = *(const float4*)(b1 + ch * 32 + 8 * g);
        const float4 bO4 = *(const float4*)(b1 + ch * 32 + 8 * g + 4);
        const f32x4 cE = {bE4.x, bE4.y, bE4.z, bE4.w};   // bias as accumulator init
        const f32x4 cO = {bO4.x, bO4.y, bO4.z, bO4.w};

        #pragma unroll
        for (int n = 0; n < 4; ++n) {
            f32x4 accE, accO;
            accE = __builtin_amdgcn_mfma_f32_16x16x32_bf16(aE0, pf[n][0], cE, 0, 0, 0);
            accE = __builtin_amdgcn_mfma_f32_16x16x32_bf16(aE1, pf[n][1], accE, 0, 0, 0);
            accO = __builtin_amdgcn_mfma_f32_16x16x32_bf16(aO0, pf[n][0], cO, 0, 0, 0);
            accO = __builtin_amdgcn_mfma_f32_16x16x32_bf16(aO1, pf[n][1], accO, 0, 0, 0);
            f32x4 mE = __builtin_elementwise_max(accE, z4);   // v_pk_max_f32 pairs
            f32x4 mO = __builtin_elementwise_max(accO, z4);
            bf16x8 hb;
            hb[0] = (short)f2bf(mE[0]); hb[1] = (short)f2bf(mE[1]);
            hb[2] = (short)f2bf(mE[2]); hb[3] = (short)f2bf(mE[3]);
            hb[4] = (short)f2bf(mO[0]); hb[5] = (short)f2bf(mO[1]);
            hb[6] = (short)f2bf(mO[2]); hb[7] = (short)f2bf(mO[3]);
            acc2[n] = __builtin_amdgcn_mfma_f32_16x16x32_bf16(w2f, hb, acc2[n], 0, 0, 0);
        }
    }

    // ---- phase 4: epilogue. acc2[n][reg] is channel 2g+(reg&1)+8*(reg>>1) (W2 row perm);
    //      ident of that channel = element 4*(reg&1) of pf[n][reg>>1]. No LDS reads. ----
    #pragma unroll
    for (int n = 0; n < 4; ++n) {
        int v = (4 * wv + n) * 16 + r16;
        int mb = __shfl(mpack, 16 * n + r16, 64);    // owner lane of voxel v (same wave)
        float al = (float)(mb & 1), mu = (float)(mb >> 1);
        int vx = v & 7, vy = (v >> 3) & 7;
        int gidx = xbase + (gz0 + wv) * 4096 + (gy0 + vy) * 64 + (gx0 + vx);
        #pragma unroll
        for (int reg = 0; reg < 4; ++reg) {
            int c = 2 * g + (reg & 1) + 8 * (reg >> 1);
            unsigned short cs = (unsigned short)pf[n][reg >> 1][(reg & 1) * 4];
            float xc = __builtin_bit_cast(float, (unsigned)cs << 16);
            out[gidx + c * 262144] = xc * al + acc2[n][reg] * mu;
        }
    }
}

extern "C" void kernel_launch(void* const* d_in, const int* in_sizes, int n_in,
                              void* d_out, int out_size, void* d_ws, size_t ws_size,
                              hipStream_t stream)
{
    const float* x      = (const float*)d_in[0];
    const float* rand_u = (const float*)d_in[1];
    const float* w1     = (const float*)d_in[2];
    const float* b1     = (const float*)d_in[3];
    const float* w2     = (const float*)d_in[4];
    float* out = (float*)d_out;
    unsigned short* wsW = (unsigned short*)d_ws;   // 20.5 KB used

    permute_w<<<dim3(1), dim3(256), 0, stream>>>(w1, w2, wsW);

    dim3 grid(8, 8, 64);
    dim3 block(256);
    nca_fused<<<grid, block, 0, stream>>>(x, rand_u, wsW, b1, out);
}

// Round 20
// 79.830 us; speedup vs baseline: 1.4952x; 1.1671x over previous
//
#include <hip/hip_runtime.h>

#define QST 600        // 6*10*10 sites per quad
#define NSITES 2400    // 4 quads

// LDS map (bytes):
//  [0,19200)      quad tile uint2[2400]: [cq][z 6][y 10][x 10], 4 bf16 channels/site
//  [19200,51968)  P bf16: 256 rows x 128B (8 slots), 16B-slot XOR swizzle slot^=(row&7)
//  total 51968 B -> 3 blocks/CU. P is WAVE-LOCAL; lgkmcnt(0)+sched_barrier, no 2nd barrier.
//  NOTE (256,3) is the operating point: (256,4) spills (R8/R17/R18); time-share spills (R19).
//
// d_ws (shorts): [0,8192) W1 frags 1024x16B (sobel cols pre-scaled by 0.125);
//                [8192,10240) W2 frags 256x16B, rows permuted so D-row r = channel
//                2*(r>>2)+(r&1)+8*((r>>1)&1)  (epilogue takes idents from pf regs, no LDS)

typedef __attribute__((ext_vector_type(8))) short bf16x8;
typedef __attribute__((ext_vector_type(4))) float f32x4;
typedef __attribute__((ext_vector_type(2))) float f32x2;

__device__ __forceinline__ unsigned short f2bf(float f) {
    __bf16 h = (__bf16)f;
    return __builtin_bit_cast(unsigned short, h);
}
__device__ __forceinline__ unsigned packbf2(float lo, float hi) {
    return (unsigned)f2bf(lo) | ((unsigned)f2bf(hi) << 16);
}
__device__ __forceinline__ float blo(unsigned u) { return __builtin_bit_cast(float, u << 16); }
__device__ __forceinline__ float bhi(unsigned u) { return __builtin_bit_cast(float, u & 0xffff0000u); }
__device__ __forceinline__ bf16x8 pack8f(const float* s, const float* scl) {
    bf16x8 o;
    #pragma unroll
    for (int k = 0; k < 8; ++k) o[k] = (short)f2bf(s[k] * scl[k & 3]);
    return o;
}

// ---- pre-pass: permute W1/W2 into lane-canonical bf16 MFMA fragments in d_ws ----
__global__ __launch_bounds__(256) void permute_w(
    const float* __restrict__ w1, const float* __restrict__ w2,
    unsigned short* __restrict__ wsW)
{
    const int t = threadIdx.x;
    const float sclW1[4] = {1.f, 0.125f, 0.125f, 0.125f};   // fold sobel /8 into W1
    const float sclId[4] = {1.f, 1.f, 1.f, 1.f};
    #pragma unroll
    for (int j = 0; j < 4; ++j) {
        int w = t + 256 * j;                 // [0,1024)
        int lane = w & 63, f = (w >> 6) & 3, ch = w >> 8;
        int r16 = lane & 15, g = lane >> 4;
        int row = ch * 32 + 8 * (r16 >> 2) + (r16 & 3) + 4 * (f >> 1);  // E: +0, O: +4
        int col = (f & 1) * 32 + g * 8;                                  // ks half
        *(bf16x8*)(wsW + w * 8) = pack8f(w1 + row * 64 + col, sclW1);
    }
    {
        int w = t;                           // [0,256)
        int lane = w & 63, ch = w >> 6;
        int r16 = lane & 15, g = lane >> 4;
        // W2 row permutation: A-row r holds channel 2*(r>>2)+(r&1)+8*((r>>1)&1)
        int ch2 = 2 * (r16 >> 2) + (r16 & 1) + 8 * ((r16 >> 1) & 1);
        *(bf16x8*)(wsW + 8192 + w * 8) = pack8f(w2 + ch2 * 128 + ch * 32 + g * 8, sclId);
    }
}

__global__ __launch_bounds__(256, 3) void nca_fused(
    const float* __restrict__ x, const float* __restrict__ rand_u,
    const unsigned short* __restrict__ wsW, const float* __restrict__ b1,
    float* __restrict__ out)
{
    __shared__ __align__(16) char smem[51968];
    uint2*          tq = (uint2*)smem;
    unsigned short* Ps = (unsigned short*)(smem + 19200);

    const int tid = threadIdx.x;

    // XCD-bijective work swizzle (R15): each XCD gets a contiguous x-fastest slab.
    const int orig = blockIdx.x + 8 * blockIdx.y + 64 * blockIdx.z;
    const int work = (orig & 7) * 512 + (orig >> 3);
    const int gx0 = (work & 7) * 8;
    const int gy0 = ((work >> 3) & 7) * 8;
    const int zb  = work >> 6;
    const int b   = zb >> 4, gz0 = (zb & 15) * 4;
    const int xbase = b * (16 * 262144);

    const int tx = tid & 7, ty = (tid >> 3) & 7, tz = tid >> 6;

    // hoist rand_u load: latency hides under staging + perception
    const float ru = rand_u[b * 262144 + (gz0 + tz) * 4096 + (gy0 + ty) * 64 + (gx0 + tx)];

    // ---- phase 1: stage tile, one (cq,z,y) row per thread (240 active) ----
    if (tid < 240) {
        int cq = tid / 60, rem = tid - cq * 60;
        int z = rem / 10, y = rem - z * 10;
        int gz = gz0 + z - 1, gy = gy0 + y - 1;
        uint4* dst = (uint4*)(tq + cq * QST + z * 100 + y * 10);   // 16B aligned
        if ((unsigned)gz < 64u && (unsigned)gy < 64u) {
            const bool lok = (gx0 > 0), rok = (gx0 < 56);
            const float* base = x + xbase + cq * (4 * 262144) + gz * 4096 + gy * 64 + gx0;
            float va[10], vb[10];
            unsigned wlo[10], whi[10];
            #pragma unroll
            for (int half = 0; half < 2; ++half) {
                #pragma unroll
                for (int cc = 0; cc < 2; ++cc) {
                    const float* bp = base + (2 * half + cc) * 262144;
                    float* v = cc ? vb : va;
                    float4 a4 = *(const float4*)(bp);
                    float4 b4 = *(const float4*)(bp + 4);
                    v[0] = lok ? bp[-1] : 0.f;
                    v[1] = a4.x; v[2] = a4.y; v[3] = a4.z; v[4] = a4.w;
                    v[5] = b4.x; v[6] = b4.y; v[7] = b4.z; v[8] = b4.w;
                    v[9] = rok ? bp[8] : 0.f;
                }
                unsigned* wdst = half ? whi : wlo;
                #pragma unroll
                for (int k = 0; k < 10; ++k) wdst[k] = packbf2(va[k], vb[k]);
            }
            #pragma unroll
            for (int k = 0; k < 5; ++k)
                dst[k] = make_uint4(wlo[2 * k], whi[2 * k], wlo[2 * k + 1], whi[2 * k + 1]);
        } else {
            #pragma unroll
            for (int k = 0; k < 5; ++k)
                dst[k] = make_uint4(0u, 0u, 0u, 0u);
        }
    }
    __syncthreads();

    // ---- phase 2: perception (separable Sobel, packed-f32 pairs), P written per-cq ----
    const int lane = tid & 63, wv = tid >> 6;
    const int g = lane >> 4, r16 = lane & 15;
    const int rowbase = (tz * 10 + ty) * 10 + tx;

    float pool3 = -1e30f;
    const f32x2 two = 2.f;

    #pragma unroll
    for (int cq = 0; cq < 4; ++cq) {
        f32x2 s1p[2], s2p[2], s3p[2];
        uint2 idq = make_uint2(0u, 0u);
        #pragma unroll
        for (int pr = 0; pr < 2; ++pr) { s1p[pr] = 0.f; s2p[pr] = 0.f; s3p[pr] = 0.f; }

        #pragma unroll
        for (int i2 = 0; i2 < 3; ++i2) {
            f32x2 Ap[2], Bp[2], Cp[2];
            #pragma unroll
            for (int pr = 0; pr < 2; ++pr) { Ap[pr] = 0.f; Bp[pr] = 0.f; Cp[pr] = 0.f; }
            #pragma unroll
            for (int j = 0; j < 3; ++j) {
                const uint2* rp = tq + cq * QST + i2 * 100 + j * 10 + rowbase;
                uint2 q0 = rp[0], q1 = rp[1], q2 = rp[2];
                f32x2 v0[2] = { {blo(q0.x), bhi(q0.x)}, {blo(q0.y), bhi(q0.y)} };
                f32x2 v1[2] = { {blo(q1.x), bhi(q1.x)}, {blo(q1.y), bhi(q1.y)} };
                f32x2 v2[2] = { {blo(q2.x), bhi(q2.x)}, {blo(q2.y), bhi(q2.y)} };
                if (cq == 0)   // alpha (c=3) = hi of second pair; nested fmax -> v_max3
                    pool3 = fmaxf(pool3, fmaxf(fmaxf(v0[1].y, v1[1].y), v2[1].y));
                if (i2 == 1 && j == 1) idq = q1;
                #pragma unroll
                for (int pr = 0; pr < 2; ++pr) {
                    f32x2 rg = __builtin_elementwise_fma(two, v1[pr], v0[pr] + v2[pr]); // g_x
                    f32x2 rd = v2[pr] - v0[pr];                                         // d_x
                    if (j == 1) {
                        Ap[pr] = __builtin_elementwise_fma(two, rg, Ap[pr]);
                        Cp[pr] = __builtin_elementwise_fma(two, rd, Cp[pr]);
                    } else {
                        Ap[pr] = Ap[pr] + rg;
                        Cp[pr] = Cp[pr] + rd;
                        if (j == 0) Bp[pr] = Bp[pr] - rg;
                        else        Bp[pr] = Bp[pr] + rg;
                    }
                }
            }
            #pragma unroll
            for (int pr = 0; pr < 2; ++pr) {
                if (i2 == 0) {
                    s1p[pr] = s1p[pr] - Ap[pr];
                    s2p[pr] = s2p[pr] + Bp[pr];
                    s3p[pr] = s3p[pr] + Cp[pr];
                } else if (i2 == 1) {
                    s2p[pr] = __builtin_elementwise_fma(two, Bp[pr], s2p[pr]);
                    s3p[pr] = __builtin_elementwise_fma(two, Cp[pr], s3p[pr]);
                } else {
                    s1p[pr] = s1p[pr] + Ap[pr];
                    s2p[pr] = s2p[pr] + Bp[pr];
                    s3p[pr] = s3p[pr] + Cp[pr];
                }
            }
        }
        // pack this cq's 8 P-dwords (sobel unscaled; /8 folded into W1) and write now
        unsigned short ide[4] = {
            (unsigned short)(idq.x & 0xffffu), (unsigned short)(idq.x >> 16),
            (unsigned short)(idq.y & 0xffffu), (unsigned short)(idq.y >> 16) };
        float s1e[4] = { s1p[0].x, s1p[0].y, s1p[1].x, s1p[1].y };
        float s2e[4] = { s2p[0].x, s2p[0].y, s2p[1].x, s2p[1].y };
        float s3e[4] = { s3p[0].x, s3p[0].y, s3p[1].x, s3p[1].y };
        unsigned pk8[8];
        #pragma unroll
        for (int e = 0; e < 4; ++e) {
            pk8[2 * e]     = (unsigned)ide[e] | ((unsigned)f2bf(s1e[e]) << 16);
            pk8[2 * e + 1] = packbf2(s2e[e], s3e[e]);
        }
        int s0 = (2 * cq)     ^ (tid & 7);
        int s1 = (2 * cq + 1) ^ (tid & 7);
        *(uint4*)(smem + 19200 + tid * 128 + s0 * 16) = make_uint4(pk8[0], pk8[1], pk8[2], pk8[3]);
        *(uint4*)(smem + 19200 + tid * 128 + s1 * 16) = make_uint4(pk8[4], pk8[5], pk8[6], pk8[7]);
    }
    // masks in a register: bit0 = alive, bit1 = msu (= smask*alive)
    int mpack = (pool3 > 0.1f) ? ((ru <= 0.5f) ? 3 : 1) : 0;

    // P is wave-local (rows 64wv..64wv+63 written and read by wave wv only)
    asm volatile("s_waitcnt lgkmcnt(0)" ::: "memory");
    __builtin_amdgcn_sched_barrier(0);

    // ---- phase 3: MFMA. GEMM1: h^T = W1p . P^T (bias in C); GEMM2: upd^T = W2p . h^T ----
    // pf[n][ks] slot ks*4+g holds channels {8ks+2g, 8ks+2g+1} x 4 features (id,s1,s2,s3)
    bf16x8 pf[4][2];
    #pragma unroll
    for (int n = 0; n < 4; ++n) {
        int v = (4 * wv + n) * 16 + r16;
        #pragma unroll
        for (int ks = 0; ks < 2; ++ks) {
            int sl = (ks * 4 + g) ^ (r16 & 7);     // slot-XOR swizzle (row&7 == r16&7)
            pf[n][ks] = *(const bf16x8*)(Ps + v * 64 + sl * 8);
        }
    }

    f32x4 acc2[4] = {{0,0,0,0},{0,0,0,0},{0,0,0,0},{0,0,0,0}};
    const f32x4 z4 = {0,0,0,0};

    #pragma unroll
    for (int ch = 0; ch < 4; ++ch) {
        const bf16x8 aE0 = *(const bf16x8*)(wsW + ((ch * 4 + 0) * 64 + lane) * 8);
        const bf16x8 aE1 = *(const bf16x8*)(wsW + ((ch * 4 + 1) * 64 + lane) * 8);
        const bf16x8 aO0 = *(const bf16x8*)(wsW + ((ch * 4 + 2) * 64 + lane) * 8);
        const bf16x8 aO1 = *(const bf16x8*)(wsW + ((ch * 4 + 3) * 64 + lane) * 8);
        const bf16x8 w2f = *(const bf16x8*)(wsW + 8192 + (ch * 64 + lane) * 8);
        const float4 bE4 = *(const float4*)(b1 + ch * 32 + 8 * g);
        const float4 bO4 = *(const float4*)(b1 + ch * 32 + 8 * g + 4);
        const f32x4 cE = {bE4.x, bE4.y, bE4.z, bE4.w};   // bias as accumulator init
        const f32x4 cO = {bO4.x, bO4.y, bO4.z, bO4.w};

        #pragma unroll
        for (int n = 0; n < 4; ++n) {
            f32x4 accE, accO;
            accE = __builtin_amdgcn_mfma_f32_16x16x32_bf16(aE0, pf[n][0], cE, 0, 0, 0);
            accE = __builtin_amdgcn_mfma_f32_16x16x32_bf16(aE1, pf[n][1], accE, 0, 0, 0);
            accO = __builtin_amdgcn_mfma_f32_16x16x32_bf16(aO0, pf[n][0], cO, 0, 0, 0);
            accO = __builtin_amdgcn_mfma_f32_16x16x32_bf16(aO1, pf[n][1], accO, 0, 0, 0);
            f32x4 mE = __builtin_elementwise_max(accE, z4);   // v_pk_max_f32 pairs
            f32x4 mO = __builtin_elementwise_max(accO, z4);
            bf16x8 hb;
            hb[0] = (short)f2bf(mE[0]); hb[1] = (short)f2bf(mE[1]);
            hb[2] = (short)f2bf(mE[2]); hb[3] = (short)f2bf(mE[3]);
            hb[4] = (short)f2bf(mO[0]); hb[5] = (short)f2bf(mO[1]);
            hb[6] = (short)f2bf(mO[2]); hb[7] = (short)f2bf(mO[3]);
            acc2[n] = __builtin_amdgcn_mfma_f32_16x16x32_bf16(w2f, hb, acc2[n], 0, 0, 0);
        }
    }

    // ---- phase 4: epilogue. acc2[n][reg] is channel 2g+(reg&1)+8*(reg>>1) (W2 row perm);
    //      ident of that channel = element 4*(reg&1) of pf[n][reg>>1]. No LDS reads. ----
    #pragma unroll
    for (int n = 0; n < 4; ++n) {
        int v = (4 * wv + n) * 16 + r16;
        int mb = __shfl(mpack, 16 * n + r16, 64);    // owner lane of voxel v (same wave)
        float al = (float)(mb & 1), mu = (float)(mb >> 1);
        int vx = v & 7, vy = (v >> 3) & 7;
        int gidx = xbase + (gz0 + wv) * 4096 + (gy0 + vy) * 64 + (gx0 + vx);
        #pragma unroll
        for (int reg = 0; reg < 4; ++reg) {
            int c = 2 * g + (reg & 1) + 8 * (reg >> 1);
            unsigned short cs = (unsigned short)pf[n][reg >> 1][(reg & 1) * 4];
            float xc = __builtin_bit_cast(float, (unsigned)cs << 16);
            out[gidx + c * 262144] = xc * al + acc2[n][reg] * mu;
        }
    }
}

extern "C" void kernel_launch(void* const* d_in, const int* in_sizes, int n_in,
                              void* d_out, int out_size, void* d_ws, size_t ws_size,
                              hipStream_t stream)
{
    const float* x      = (const float*)d_in[0];
    const float* rand_u = (const float*)d_in[1];
    const float* w1     = (const float*)d_in[2];
    const float* b1     = (const float*)d_in[3];
    const float* w2     = (const float*)d_in[4];
    float* out = (float*)d_out;
    unsigned short* wsW = (unsigned short*)d_ws;   // 20.5 KB used

    permute_w<<<dim3(1), dim3(256), 0, stream>>>(w1, w2, wsW);

    dim3 grid(8, 8, 64);
    dim3 block(256);
    nca_fused<<<grid, block, 0, stream>>>(x, rand_u, wsW, b1, out);
}